// Round 2
// baseline (179.634 us; speedup 1.0000x reference)
//
#include <hip/hip_runtime.h>
#include <hip/hip_bf16.h>

// Problem constants (match reference): B=64, L=2048, H=256, K=32
#define LL 2048
#define BB 64
#define HH 256
#define KK 32

__device__ __forceinline__ float softplus_f(float x) {
    // matches jax.nn.softplus = log1p(exp(x)) for the value range here (|x| <~ 20)
    return x > 20.f ? x : log1pf(__expf(x));
}

// One block per l (timestep). 256 threads. Loops over b=0..63, skipping masked rows.
// Phase A: each thread computes u = hidden[h], v = o*tanh(c_sim) for h = tid, stages in LDS.
// Phase B: thread (c = tid>>3, kg = tid&7) holds W[(c*8+j), kg*4+kk] in 32 registers,
//          accumulates 8h x 4k partial dots for both u and v, writes 8 floats to LDS P.
// Reduce:  wave 0 sums P over the 32 h-chunks, applies bias/softplus, produces the
//          row's contribution  coef * sum_k softplus(v-dot) - log(softplus(u-dot at e)).
__global__ __launch_bounds__(256) void nhll_main(
    const int*   __restrict__ events,   // [B, L]
    const int*   __restrict__ lens,     // [B]
    const float* __restrict__ ttime,    // [B]
    const float* __restrict__ hidden,   // [L, B, H]
    const float* __restrict__ cell,     // [L, B, H]
    const float* __restrict__ ctarg,    // [L, B, H]
    const float* __restrict__ outp,     // [L, B, H]
    const float* __restrict__ decay,    // [L, B, H]
    const float* __restrict__ simt,     // [L, B]
    const float* __restrict__ W,        // [H, K]
    const float* __restrict__ bias,     // [K]
    float*       __restrict__ partial)  // [gridDim.x]
{
    __shared__ __align__(16) float u_s[HH];
    __shared__ __align__(16) float v_s[HH];
    __shared__ __align__(16) float P[32 * 64];   // [c-chunk][k*2 + {u,v}]
    __shared__ float bias_s[KK];
    __shared__ int   len_s[BB];
    __shared__ float tt_s[BB];

    const int tid = threadIdx.x;
    const int l   = blockIdx.x;
    const int c   = tid >> 3;   // h-chunk 0..31 (8 h each)
    const int kg  = tid & 7;    // k-group 0..7 (4 k each)

    // W slice into registers: wreg[j].{x,y,z,w} = W[(c*8+j)*K + kg*4 + {0..3}]
    float4 wreg[8];
#pragma unroll
    for (int j = 0; j < 8; ++j)
        wreg[j] = *reinterpret_cast<const float4*>(&W[(c * 8 + j) * KK + kg * 4]);

    if (tid < BB) { len_s[tid] = lens[tid]; tt_s[tid] = ttime[tid]; }
    if (tid < KK) { bias_s[tid] = bias[tid]; }
    __syncthreads();

    float acc = 0.f;

    for (int b = 0; b < BB; ++b) {
        const int len = len_s[b];
        if (l >= len) continue;          // block-uniform branch, barriers safely skipped
        const int r    = l * BB + b;
        const int base = r * HH;

        // ---- phase A: per-h streaming compute ----
        const float u  = hidden[base + tid];
        const float cc = cell[base + tid];
        const float ct = ctarg[base + tid];
        const float oo = outp[base + tid];
        const float dd = decay[base + tid];
        const float st = simt[r];
        const float cs = ct + (cc - ct) * __expf(-dd * st);
        // tanh via rational exp form (|cs| <~ 12 for this data; e^{2cs} cannot overflow)
        const float e2 = __expf(2.f * cs);
        const float v  = oo * ((e2 - 1.f) / (e2 + 1.f));
        u_s[tid] = u;
        v_s[tid] = v;
        __syncthreads();

        // ---- phase B: 8h x 4k register-tile matvec (u and v) ----
        const float4* u4 = reinterpret_cast<const float4*>(u_s);
        const float4* v4 = reinterpret_cast<const float4*>(v_s);
        const float4 ua = u4[c * 2], ub = u4[c * 2 + 1];
        const float4 va = v4[c * 2], vb = v4[c * 2 + 1];
        const float us[8] = {ua.x, ua.y, ua.z, ua.w, ub.x, ub.y, ub.z, ub.w};
        const float vs[8] = {va.x, va.y, va.z, va.w, vb.x, vb.y, vb.z, vb.w};
        float4 aU = {0, 0, 0, 0}, aV = {0, 0, 0, 0};
#pragma unroll
        for (int j = 0; j < 8; ++j) {
            const float4 w = wreg[j];
            const float uj = us[j], vj = vs[j];
            aU.x = fmaf(uj, w.x, aU.x); aU.y = fmaf(uj, w.y, aU.y);
            aU.z = fmaf(uj, w.z, aU.z); aU.w = fmaf(uj, w.w, aU.w);
            aV.x = fmaf(vj, w.x, aV.x); aV.y = fmaf(vj, w.y, aV.y);
            aV.z = fmaf(vj, w.z, aV.z); aV.w = fmaf(vj, w.w, aV.w);
        }
        // P slot layout: slot = k*2 + w  (w: 0=u, 1=v); k = kg*4+kk
        float4* P4 = reinterpret_cast<float4*>(P);
        P4[c * 16 + kg * 2 + 0] = make_float4(aU.x, aV.x, aU.y, aV.y);
        P4[c * 16 + kg * 2 + 1] = make_float4(aU.z, aV.z, aU.w, aV.w);
        __syncthreads();

        // ---- reduce (wave 0 only): sum over the 32 h-chunks ----
        if (tid < 64) {
            const int k = tid & 31;           // key index
            const int w = tid >> 5;           // 0 = u-dot, 1 = v-dot
            const int slot = k * 2 + w;
            float S = 0.f;
#pragma unroll
            for (int c2 = 0; c2 < 32; ++c2) S += P[c2 * 64 + slot];

            const float x  = S + bias_s[k];
            float sp = softplus_f(x);
            // butterfly within each 32-lane half (upper half carries the v-sum)
            for (int m = 1; m < 32; m <<= 1) sp += __shfl_xor(sp, m, 64);

            const int   e    = events[b * LL + l + 1];  // shifted event (l+1 <= 2046 here)
            const float Su   = __shfl(S, e, 64);        // u-dot at k=e (lane e, w=0)
            const float sumv = __shfl(sp, 32, 64);      // sum_k softplus(v-dot + bias)

            if (tid == 0) {
                const float t1   = __logf(softplus_f(Su + bias_s[e]));
                const float coef = tt_s[b] / (float)len;
                acc += coef * sumv - t1;    // simulated_ll - original_ll, per row
            }
        }
    }
    if (tid == 0) partial[blockIdx.x] = acc;
}

// Output is the reference's dtype: a single float32 scalar.
__global__ __launch_bounds__(256) void nhll_finalize(
    const float* __restrict__ partial, float* __restrict__ out)
{
    __shared__ float red[4];
    float s = 0.f;
    for (int i = threadIdx.x; i < LL; i += 256) s += partial[i];
    for (int m = 1; m < 64; m <<= 1) s += __shfl_xor(s, m, 64);
    if ((threadIdx.x & 63) == 0) red[threadIdx.x >> 6] = s;
    __syncthreads();
    if (threadIdx.x == 0)
        out[0] = red[0] + red[1] + red[2] + red[3];
}

extern "C" void kernel_launch(void* const* d_in, const int* in_sizes, int n_in,
                              void* d_out, int out_size, void* d_ws, size_t ws_size,
                              hipStream_t stream) {
    const int*   events = (const int*)  d_in[0];   // event_seqs  [B,L] int32
    const int*   lens   = (const int*)  d_in[1];   // seqs_length [B]   int32
    const float* ttime  = (const float*)d_in[2];   // total_time  [B]
    const float* hidden = (const float*)d_in[3];   // [L,B,H]
    const float* cell   = (const float*)d_in[4];   // [L,B,H]
    const float* ctarg  = (const float*)d_in[5];   // [L,B,H]
    const float* outp   = (const float*)d_in[6];   // [L,B,H]
    const float* decay  = (const float*)d_in[7];   // [L,B,H]
    const float* simt   = (const float*)d_in[8];   // [L,B]
    const float* W      = (const float*)d_in[9];   // [H,K]
    const float* bias   = (const float*)d_in[10];  // [K]

    float* part = (float*)d_ws;                    // 2048 floats
    float* out  = (float*)d_out;

    nhll_main<<<LL, 256, 0, stream>>>(events, lens, ttime, hidden, cell, ctarg,
                                      outp, decay, simt, W, bias, part);
    nhll_finalize<<<1, 256, 0, stream>>>(part, out);
}

// Round 3
// 114.462 us; speedup vs baseline: 1.5694x; 1.5694x over previous
//
#include <hip/hip_runtime.h>
#include <hip/hip_bf16.h>

// Problem constants (match reference): B=64, L=2048, H=256, K=32
#define LL 2048
#define BB 64
#define HH 256
#define KK 32

__device__ __forceinline__ float softplus_f(float x) {
    // log(1+e^x); 2%-tolerance-loose fast form
    return x > 20.f ? x : __logf(1.f + __expf(x));
}

// Wave-per-row design. One block per l (2048 blocks, 256 threads = 4 waves).
// Stage W^T (32KB) + valid-b list once (single barrier), then each wave
// independently processes rows (l, b) with float4 loads, in-register matvec
// against LDS W^T, and in-wave shuffle reductions. No barriers in main loop.
__global__ __launch_bounds__(256) void nhll_main(
    const int*   __restrict__ events,   // [B, L]
    const int*   __restrict__ lens,     // [B]
    const float* __restrict__ ttime,    // [B]
    const float* __restrict__ hidden,   // [L, B, H]
    const float* __restrict__ cell,     // [L, B, H]
    const float* __restrict__ ctarg,    // [L, B, H]
    const float* __restrict__ outp,     // [L, B, H]
    const float* __restrict__ decay,    // [L, B, H]
    const float* __restrict__ simt,     // [L, B]
    const float* __restrict__ W,        // [H, K]
    const float* __restrict__ bias,     // [K]
    float*       __restrict__ partial)  // [gridDim.x * 4]
{
    __shared__ __align__(16) float WT[KK][HH];   // transposed W, 32 KB
    __shared__ float bias_s[KK];
    __shared__ float coef_s[BB];
    __shared__ int   blist[BB];
    __shared__ int   cnt_s;

    const int tid  = threadIdx.x;
    const int lane = tid & 63;
    const int q    = tid >> 6;      // wave id 0..3
    const int l    = blockIdx.x;

    // stage W^T: thread t owns h-row t (writes spread across banks: free)
    {
        const float* wrow = &W[tid * KK];
#pragma unroll
        for (int k = 0; k < KK; ++k) WT[k][tid] = wrow[k];
    }
    if (tid < KK) bias_s[tid] = bias[tid];
    if (tid < BB) {   // wave 0 exactly
        const int ln = lens[tid];
        coef_s[tid] = ttime[tid] / (float)ln;
        const unsigned long long m = __ballot(l < ln);
        if (l < ln) {
            const int rank = __popcll(m & ((1ull << tid) - 1));
            blist[rank] = tid;
        }
        if (tid == 0) cnt_s = __popcll(m);
    }
    __syncthreads();

    const int count = cnt_s;
    const int h0    = lane * 4;
    float acc = 0.f;

    for (int idx = q; idx < count; idx += 4) {
        const int  b    = blist[idx];
        const int  r    = l * BB + b;
        const long base = (long)r * HH + h0;

        const float4 hh = *(const float4*)&hidden[base];
        const float4 cc = *(const float4*)&cell[base];
        const float4 ct = *(const float4*)&ctarg[base];
        const float4 oo = *(const float4*)&outp[base];
        const float4 dd = *(const float4*)&decay[base];
        const float  st = simt[r];
        const int    e  = events[b * LL + l + 1];   // l+1 <= 2046 (len <= 2046)

        // v = o * tanh(ct + (cc-ct)*exp(-dd*st));  |cs| <~ 12 so e^{2cs} finite
        float4 v4;
        {
            float cs, e2;
            cs = ct.x + (cc.x - ct.x) * __expf(-dd.x * st); e2 = __expf(2.f * cs); v4.x = oo.x * ((e2 - 1.f) / (e2 + 1.f));
            cs = ct.y + (cc.y - ct.y) * __expf(-dd.y * st); e2 = __expf(2.f * cs); v4.y = oo.y * ((e2 - 1.f) / (e2 + 1.f));
            cs = ct.z + (cc.z - ct.z) * __expf(-dd.z * st); e2 = __expf(2.f * cs); v4.z = oo.z * ((e2 - 1.f) / (e2 + 1.f));
            cs = ct.w + (cc.w - ct.w) * __expf(-dd.w * st); e2 = __expf(2.f * cs); v4.w = oo.w * ((e2 - 1.f) / (e2 + 1.f));
        }

        // term 1: hidden-dot at the single gathered column k = e
        const float4 we = *(const float4*)&WT[e][h0];
        float Su = hh.x * we.x + hh.y * we.y + hh.z * we.z + hh.w * we.w;
#pragma unroll
        for (int m = 1; m < 64; m <<= 1) Su += __shfl_xor(Su, m, 64);

        // term 2: v-matvec, per-lane partial dot for all 32 k
        float accV[KK];
#pragma unroll
        for (int k = 0; k < KK; ++k) {
            const float4 w4 = *(const float4*)&WT[k][h0];
            accV[k] = v4.x * w4.x + v4.y * w4.y + v4.z * w4.z + v4.w * w4.w;
        }
        // fold upper/lower wave halves
#pragma unroll
        for (int k = 0; k < KK; ++k) accV[k] += __shfl_xor(accV[k], 32, 64);
        // recursive-halving reduce-scatter within 32-lane groups:
        // after this, lane holds accV[0] = S_v[k = lane&31]
#define RS_STEP(M, V)                                                         \
        {                                                                     \
            const bool hi = (lane & (M)) != 0;                                \
            _Pragma("unroll")                                                 \
            for (int i = 0; i < (V); ++i) {                                   \
                const float keep = hi ? accV[i + (V)] : accV[i];              \
                const float sent = hi ? accV[i] : accV[i + (V)];              \
                accV[i] = keep + __shfl_xor(sent, (M), 64);                   \
            }                                                                 \
        }
        RS_STEP(16, 16)
        RS_STEP(8, 8)
        RS_STEP(4, 4)
        RS_STEP(2, 2)
        RS_STEP(1, 1)
#undef RS_STEP

        const int k = lane & 31;
        float sp = softplus_f(accV[0] + bias_s[k]);
#pragma unroll
        for (int m = 1; m < 32; m <<= 1) sp += __shfl_xor(sp, m, 64);
        // sp = sum_k softplus(S_v[k] + bias[k]) on every lane

        acc += coef_s[b] * sp - __logf(softplus_f(Su + bias_s[e]));
    }

    if (lane == 0) partial[blockIdx.x * 4 + q] = acc;
}

// Output is the reference's dtype: a single float32 scalar.
__global__ __launch_bounds__(256) void nhll_finalize(
    const float* __restrict__ partial, float* __restrict__ out)
{
    __shared__ float red[4];
    float s = 0.f;
    for (int i = threadIdx.x; i < LL * 4; i += 256) s += partial[i];
    for (int m = 1; m < 64; m <<= 1) s += __shfl_xor(s, m, 64);
    if ((threadIdx.x & 63) == 0) red[threadIdx.x >> 6] = s;
    __syncthreads();
    if (threadIdx.x == 0)
        out[0] = red[0] + red[1] + red[2] + red[3];
}

extern "C" void kernel_launch(void* const* d_in, const int* in_sizes, int n_in,
                              void* d_out, int out_size, void* d_ws, size_t ws_size,
                              hipStream_t stream) {
    const int*   events = (const int*)  d_in[0];   // event_seqs  [B,L] int32
    const int*   lens   = (const int*)  d_in[1];   // seqs_length [B]   int32
    const float* ttime  = (const float*)d_in[2];   // total_time  [B]
    const float* hidden = (const float*)d_in[3];   // [L,B,H]
    const float* cell   = (const float*)d_in[4];   // [L,B,H]
    const float* ctarg  = (const float*)d_in[5];   // [L,B,H]
    const float* outp   = (const float*)d_in[6];   // [L,B,H]
    const float* decay  = (const float*)d_in[7];   // [L,B,H]
    const float* simt   = (const float*)d_in[8];   // [L,B]
    const float* W      = (const float*)d_in[9];   // [H,K]
    const float* bias   = (const float*)d_in[10];  // [K]

    float* part = (float*)d_ws;                    // 8192 floats (32 KB)
    float* out  = (float*)d_out;

    nhll_main<<<LL, 256, 0, stream>>>(events, lens, ttime, hidden, cell, ctarg,
                                      outp, decay, simt, W, bias, part);
    nhll_finalize<<<1, 256, 0, stream>>>(part, out);
}

// Round 4
// 96.714 us; speedup vs baseline: 1.8574x; 1.1835x over previous
//
#include <hip/hip_runtime.h>
#include <hip/hip_bf16.h>

// Problem constants (match reference): B=64, L=2048, H=256, K=32
#define LL 2048
#define BB 64
#define HH 256
#define KK 32

#define NB  1024   // blocks (4 resident per CU)
#define WPB 4      // waves per block

__device__ __forceinline__ float softplus_f(float x) {
    return x > 20.f ? x : __logf(1.f + __expf(x));
}

// Balanced wave-per-row design. Fixed grid NB x 256. Each block stages W^T
// (32 KB LDS) + prefix-sum of lens once (one barrier), then each wave
// grid-strides over a FLAT valid-row index i in [0,T), i -> (b,l) via uniform
// binary search. No barriers, perfectly uniform work (<=1 row skew per wave).
__global__ __launch_bounds__(256) void nhll_main(
    const int*   __restrict__ events,   // [B, L]
    const int*   __restrict__ lens,     // [B]
    const float* __restrict__ ttime,    // [B]
    const float* __restrict__ hidden,   // [L, B, H]
    const float* __restrict__ cell,     // [L, B, H]
    const float* __restrict__ ctarg,    // [L, B, H]
    const float* __restrict__ outp,     // [L, B, H]
    const float* __restrict__ decay,    // [L, B, H]
    const float* __restrict__ simt,     // [L, B]
    const float* __restrict__ W,        // [H, K]
    const float* __restrict__ bias,     // [K]
    float*       __restrict__ partial)  // [NB]
{
    __shared__ __align__(16) float WT[KK][HH];   // transposed W, 32 KB
    __shared__ float bias_s[KK];
    __shared__ float coef_s[BB];
    __shared__ int   pfx[BB + 1];                // prefix sums of lens
    __shared__ float wacc[WPB];

    const int tid  = threadIdx.x;
    const int lane = tid & 63;
    const int q    = tid >> 6;      // wave id in block

    // stage W^T: thread t owns h-row t
    {
        const float* wrow = &W[tid * KK];
#pragma unroll
        for (int k = 0; k < KK; ++k) WT[k][tid] = wrow[k];
    }
    if (tid < KK) bias_s[tid] = bias[tid];
    if (tid < BB) {                 // wave 0 exactly: scan lens
        const int ln = lens[tid];
        coef_s[tid] = ttime[tid] / (float)ln;
        int s = ln;
#pragma unroll
        for (int m = 1; m < 64; m <<= 1) {
            const int t = __shfl_up(s, m, 64);
            if (lane >= m) s += t;
        }
        pfx[tid + 1] = s;
        if (tid == 0) pfx[0] = 0;
    }
    __syncthreads();

    const int T  = pfx[BB];
    const int h0 = lane * 4;
    float acc = 0.f;

    for (int i = blockIdx.x * WPB + q; i < T; i += NB * WPB) {
        // uniform binary search: largest b with pfx[b] <= i
        int lo = 0, hi = BB;
#pragma unroll
        for (int s = 0; s < 6; ++s) {
            const int mid = (lo + hi) >> 1;
            if (pfx[mid] <= i) lo = mid; else hi = mid;
        }
        const int  b    = lo;
        const int  l    = i - pfx[b];
        const int  r    = l * BB + b;
        const long base = (long)r * HH + h0;

        const float4 hh = *(const float4*)&hidden[base];
        const float4 cc = *(const float4*)&cell[base];
        const float4 ct = *(const float4*)&ctarg[base];
        const float4 oo = *(const float4*)&outp[base];
        const float4 dd = *(const float4*)&decay[base];
        const float  st = simt[r];
        const int    e  = events[b * LL + l + 1];   // l+1 <= 2046: in-bounds

        // v = o * tanh(ct + (cc-ct)*exp(-dd*st))
        float4 v4;
        {
            float cs, e2;
            cs = ct.x + (cc.x - ct.x) * __expf(-dd.x * st); e2 = __expf(2.f * cs); v4.x = oo.x * ((e2 - 1.f) / (e2 + 1.f));
            cs = ct.y + (cc.y - ct.y) * __expf(-dd.y * st); e2 = __expf(2.f * cs); v4.y = oo.y * ((e2 - 1.f) / (e2 + 1.f));
            cs = ct.z + (cc.z - ct.z) * __expf(-dd.z * st); e2 = __expf(2.f * cs); v4.z = oo.z * ((e2 - 1.f) / (e2 + 1.f));
            cs = ct.w + (cc.w - ct.w) * __expf(-dd.w * st); e2 = __expf(2.f * cs); v4.w = oo.w * ((e2 - 1.f) / (e2 + 1.f));
        }

        // term 1: hidden-dot at the single gathered column k = e
        const float4 we = *(const float4*)&WT[e][h0];
        float Su = hh.x * we.x + hh.y * we.y + hh.z * we.z + hh.w * we.w;
#pragma unroll
        for (int m = 1; m < 64; m <<= 1) Su += __shfl_xor(Su, m, 64);

        // term 2: per-lane partial dots for all 32 k
        float accV[KK];
#pragma unroll
        for (int k = 0; k < KK; ++k) {
            const float4 w4 = *(const float4*)&WT[k][h0];
            accV[k] = v4.x * w4.x + v4.y * w4.y + v4.z * w4.z + v4.w * w4.w;
        }
        // reduce-scatter over masks 32..2 (fold included): 31 shfl.
        // Ends with accV[0] = partial S_v[k=(lane>>1)&31] over lanes sharing bit0.
#define RS_STEP(M, V)                                                         \
        {                                                                     \
            const bool hi_ = (lane & (M)) != 0;                               \
            _Pragma("unroll")                                                 \
            for (int ii = 0; ii < (V); ++ii) {                                \
                const float keep = hi_ ? accV[ii + (V)] : accV[ii];           \
                const float sent = hi_ ? accV[ii] : accV[ii + (V)];           \
                accV[ii] = keep + __shfl_xor(sent, (M), 64);                  \
            }                                                                 \
        }
        RS_STEP(32, 16)
        RS_STEP(16, 8)
        RS_STEP(8, 4)
        RS_STEP(4, 2)
        RS_STEP(2, 1)
#undef RS_STEP
        accV[0] += __shfl_xor(accV[0], 1, 64);      // pair-fix: full S_v[k]

        const int k = (lane >> 1) & 31;
        float sp = softplus_f(accV[0] + bias_s[k]);
#pragma unroll
        for (int m = 2; m <= 32; m <<= 1) sp += __shfl_xor(sp, m, 64);
        // sp = sum_k softplus(S_v[k] + bias[k])  (32 distinct k per bit0-class)

        acc += coef_s[b] * sp - __logf(softplus_f(Su + bias_s[e]));
    }

    if (lane == 0) wacc[q] = acc;
    __syncthreads();
    if (tid == 0) partial[blockIdx.x] = wacc[0] + wacc[1] + wacc[2] + wacc[3];
}

// Output is the reference's dtype: a single float32 scalar.
__global__ __launch_bounds__(256) void nhll_finalize(
    const float* __restrict__ partial, float* __restrict__ out)
{
    __shared__ float red[4];
    float s = 0.f;
    for (int i = threadIdx.x; i < NB; i += 256) s += partial[i];
    for (int m = 1; m < 64; m <<= 1) s += __shfl_xor(s, m, 64);
    if ((threadIdx.x & 63) == 0) red[threadIdx.x >> 6] = s;
    __syncthreads();
    if (threadIdx.x == 0)
        out[0] = red[0] + red[1] + red[2] + red[3];
}

extern "C" void kernel_launch(void* const* d_in, const int* in_sizes, int n_in,
                              void* d_out, int out_size, void* d_ws, size_t ws_size,
                              hipStream_t stream) {
    const int*   events = (const int*)  d_in[0];   // event_seqs  [B,L] int32
    const int*   lens   = (const int*)  d_in[1];   // seqs_length [B]   int32
    const float* ttime  = (const float*)d_in[2];   // total_time  [B]
    const float* hidden = (const float*)d_in[3];   // [L,B,H]
    const float* cell   = (const float*)d_in[4];   // [L,B,H]
    const float* ctarg  = (const float*)d_in[5];   // [L,B,H]
    const float* outp   = (const float*)d_in[6];   // [L,B,H]
    const float* decay  = (const float*)d_in[7];   // [L,B,H]
    const float* simt   = (const float*)d_in[8];   // [L,B]
    const float* W      = (const float*)d_in[9];   // [H,K]
    const float* bias   = (const float*)d_in[10];  // [K]

    float* part = (float*)d_ws;                    // NB floats (4 KB)
    float* out  = (float*)d_out;

    nhll_main<<<NB, 256, 0, stream>>>(events, lens, ttime, hidden, cell, ctarg,
                                      outp, decay, simt, W, bias, part);
    nhll_finalize<<<1, 256, 0, stream>>>(part, out);
}

// Round 5
// 81.900 us; speedup vs baseline: 2.1933x; 1.1809x over previous
//
#include <hip/hip_runtime.h>

// Problem constants (match reference): B=64, L=2048, H=256, K=32
#define LL 2048
#define BB 64
#define HH 256
#define KK 32

#define NBLK 768   // 3 blocks/CU (LDS-limited), all resident
#define WPB  4     // waves per block

typedef __attribute__((ext_vector_type(8))) short  short8;   // 8 bf16 (4 VGPRs)
typedef __attribute__((ext_vector_type(4))) float  f32x4;

__device__ __forceinline__ float softplus_f(float x) {
    return x > 20.f ? x : __logf(1.f + __expf(x));
}
// round-to-nearest-even fp32 -> bf16
__device__ __forceinline__ unsigned int f2bf(float x) {
    unsigned u = __builtin_bit_cast(unsigned, x);
    return (u + 0x7FFFu + ((u >> 16) & 1u)) >> 16;
}

// Per wave-tile: 8 flat rows. A-tile[16][256] bf16 = rows 0-7: v = o*tanh(c_sim),
// rows 8-15: hidden. One MFMA pass (8 K-chunks x 2 N-tiles) gives C[16][32] =
// {v-dots, hidden-dots} vs W. Epilogue: term2 = coef * sum_k softplus(C_v + bias),
// term1 = log(softplus(C_h at gathered column e)). No barriers in the main loop.
__global__ __launch_bounds__(256) void nhll_main(
    const int*   __restrict__ events,   // [B, L]
    const int*   __restrict__ lens,     // [B]
    const float* __restrict__ ttime,    // [B]
    const float* __restrict__ hidden,   // [L, B, H]
    const float* __restrict__ cell,     // [L, B, H]
    const float* __restrict__ ctarg,    // [L, B, H]
    const float* __restrict__ outp,     // [L, B, H]
    const float* __restrict__ decay,    // [L, B, H]
    const float* __restrict__ simt,     // [L, B]
    const float* __restrict__ W,        // [H, K]
    const float* __restrict__ bias,     // [K]
    float*       __restrict__ partial)  // [NBLK]
{
    // WTs: W^T in bf16, [n][k] k-contiguous (= B-fragment layout), XOR-swizzled.
    __shared__ __align__(16) char  WTs[KK * HH * 2];        // 16 KB
    __shared__ __align__(16) char  Als[WPB][16 * HH * 2];   // 8 KB per wave
    __shared__ int   pfx[BB + 1];
    __shared__ float coef_s[BB];
    __shared__ float bias_s[KK];
    __shared__ float wacc[WPB];

    const int tid  = threadIdx.x;
    const int lane = tid & 63;
    const int q    = tid >> 6;

    // ---- prologue: stage swizzled bf16 W^T ----
    {
        const int n  = tid & 31;                 // output column 0..31
        const int o0 = (tid >> 5) * 4;           // first k-octet of 4
#pragma unroll
        for (int rep = 0; rep < 4; ++rep) {
            const int ko = o0 + rep;             // k-octet 0..31 (k = 8*ko..8*ko+7)
            unsigned p[4];
#pragma unroll
            for (int jj = 0; jj < 4; ++jj) {
                const unsigned a = f2bf(W[(ko * 8 + 2 * jj)     * KK + n]);
                const unsigned b = f2bf(W[(ko * 8 + 2 * jj + 1) * KK + n]);
                p[jj] = a | (b << 16);
            }
            const int off = (n * 512 + ko * 16) ^ ((n & 7) << 4);
            *(uint4*)(WTs + off) = make_uint4(p[0], p[1], p[2], p[3]);
        }
    }
    if (tid < KK) bias_s[tid] = bias[tid];
    if (tid < BB) {                              // wave 0: scan lens
        const int ln = lens[tid];
        coef_s[tid] = ttime[tid] / (float)ln;
        int s = ln;
#pragma unroll
        for (int mm = 1; mm < 64; mm <<= 1) {
            const int t = __shfl_up(s, mm, 64);
            if (lane >= mm) s += t;
        }
        pfx[tid + 1] = s;
        if (tid == 0) pfx[0] = 0;
    }
    __syncthreads();

    const int   T      = pfx[BB];
    const int   ntiles = (T + 7) >> 3;
    const int   nwav   = NBLK * WPB;
    const int   g      = lane >> 4;
    const int   m      = lane & 15;
    const float bl     = bias_s[m];
    const float bh     = bias_s[16 + m];
    char* Aw = Als[q];
    float acc = 0.f;

    for (int tile = blockIdx.x * WPB + q; tile < ntiles; tile += nwav) {
        const int i0 = tile * 8;
        // binary search: largest b with pfx[b] <= i0
        int lo = 0, hi = BB;
#pragma unroll
        for (int s = 0; s < 6; ++s) {
            const int mid = (lo + hi) >> 1;
            if (pfx[mid] <= i0) lo = mid; else hi = mid;
        }
        int b = lo, cur = pfx[b], nxt = pfx[b + 1];

        float coefs[8]; int es[8]; int validm = 0;

        // ---- stage A-tile: 8 rows, v into rows 0-7, hidden into rows 8-15 ----
#pragma unroll
        for (int rr = 0; rr < 8; ++rr) {
            int i = i0 + rr;
            const int valid = (i < T) ? 1 : 0;
            if (!valid) i = T - 1;               // clamp: harmless data, masked below
            while (i >= nxt) { ++b; cur = nxt; nxt = pfx[b + 1]; }
            const int  l    = i - cur;
            const int  r    = l * BB + b;
            const long base = (long)r * HH + lane * 4;

            const float4 hh4 = *(const float4*)&hidden[base];
            const float4 cc4 = *(const float4*)&cell[base];
            const float4 ct4 = *(const float4*)&ctarg[base];
            const float4 oo4 = *(const float4*)&outp[base];
            const float4 dd4 = *(const float4*)&decay[base];
            const float  st  = simt[r];
            es[rr]    = valid ? events[b * LL + l + 1] : 0;   // l+1 <= 2046
            coefs[rr] = valid ? coef_s[b] : 0.f;
            validm   |= valid << rr;

            float4 v4;
            {
                float cs, e2;
                cs = ct4.x + (cc4.x - ct4.x) * __expf(-dd4.x * st); e2 = __expf(2.f * cs); v4.x = oo4.x * ((e2 - 1.f) / (e2 + 1.f));
                cs = ct4.y + (cc4.y - ct4.y) * __expf(-dd4.y * st); e2 = __expf(2.f * cs); v4.y = oo4.y * ((e2 - 1.f) / (e2 + 1.f));
                cs = ct4.z + (cc4.z - ct4.z) * __expf(-dd4.z * st); e2 = __expf(2.f * cs); v4.z = oo4.z * ((e2 - 1.f) / (e2 + 1.f));
                cs = ct4.w + (cc4.w - ct4.w) * __expf(-dd4.w * st); e2 = __expf(2.f * cs); v4.w = oo4.w * ((e2 - 1.f) / (e2 + 1.f));
            }
            // A layout: [row][k] bf16 contiguous, byte = row*512 + k*2, swizzle ((row&7)<<4)
            const int offv = ((rr)     * 512 + lane * 8) ^ ((rr & 7) << 4);
            const int offh = ((8 + rr) * 512 + lane * 8) ^ ((rr & 7) << 4);  // (8+rr)&7 == rr&7
            *(uint2*)(Aw + offv) = make_uint2(f2bf(v4.x)  | (f2bf(v4.y) << 16),
                                              f2bf(v4.z)  | (f2bf(v4.w) << 16));
            *(uint2*)(Aw + offh) = make_uint2(f2bf(hh4.x) | (f2bf(hh4.y) << 16),
                                              f2bf(hh4.z) | (f2bf(hh4.w) << 16));
        }

        // ---- MFMA: C[16 rows][32 cols], 8 K-chunks x 2 N-tiles ----
        f32x4 C0 = {0.f, 0.f, 0.f, 0.f}, C1 = {0.f, 0.f, 0.f, 0.f};
        const int abase = m * 512 + 16 * g;          // A: row=m, k-slice 8g
        const int b1add = 16 * 512;                  // B tile 1: n = 16+m
        const int swz   = (m & 7) << 4;
#pragma unroll
        for (int c = 0; c < 8; ++c) {
            const short8 a  = *(const short8*)(Aw  + ((abase + 64 * c) ^ swz));
            const short8 w0 = *(const short8*)(WTs + ((abase + 64 * c) ^ swz));
            const short8 w1 = *(const short8*)(WTs + ((abase + b1add + 64 * c) ^ swz));
            C0 = __builtin_amdgcn_mfma_f32_16x16x32_bf16(a, w0, C0, 0, 0, 0);
            C1 = __builtin_amdgcn_mfma_f32_16x16x32_bf16(a, w1, C1, 0, 0, 0);
        }

        // ---- term 2: v-rows 0..7 live in lane-groups 0,1 (row = 4g+reg) ----
        float spv[4];
#pragma unroll
        for (int rg = 0; rg < 4; ++rg)
            spv[rg] = softplus_f(C0[rg] + bl) + softplus_f(C1[rg] + bh);
#pragma unroll
        for (int mk = 1; mk <= 8; mk <<= 1) {
#pragma unroll
            for (int rg = 0; rg < 4; ++rg) spv[rg] += __shfl_xor(spv[rg], mk, 64);
        }
        float t2 = 0.f;
#pragma unroll
        for (int rg = 0; rg < 4; ++rg) {
            const float cf = (g == 0) ? coefs[rg] : coefs[4 + rg];
            t2 += cf * spv[rg];
        }
        if (m == 0 && g < 2) acc += t2;

        // ---- term 1: hidden-row (8+rr) gathered at column e ----
        float kv = 0.f, kb = 0.f;
#pragma unroll
        for (int rr = 0; rr < 8; ++rr) {
            const int   e    = es[rr];
            const float cand = (e < 16) ? C0[rr & 3] : C1[rr & 3];
            const float val  = __shfl(cand, 32 + ((rr >> 2) << 4) + (e & 15), 64);
            const float bsel = (e < 16) ? bl : bh;
            const float be   = __shfl(bsel, e & 15, 64);
            kv = (lane == rr) ? val : kv;
            kb = (lane == rr) ? be  : kb;
        }
        if (lane < 8 && ((validm >> lane) & 1))
            acc -= __logf(softplus_f(kv + kb));
    }

    // wave reduce + block reduce
#pragma unroll
    for (int mk = 1; mk < 64; mk <<= 1) acc += __shfl_xor(acc, mk, 64);
    if (lane == 0) wacc[q] = acc;
    __syncthreads();
    if (tid == 0) partial[blockIdx.x] = wacc[0] + wacc[1] + wacc[2] + wacc[3];
}

// Output: single float32 scalar.
__global__ __launch_bounds__(256) void nhll_finalize(
    const float* __restrict__ partial, float* __restrict__ out)
{
    __shared__ float red[4];
    float s = 0.f;
    for (int i = threadIdx.x; i < NBLK; i += 256) s += partial[i];
    for (int mk = 1; mk < 64; mk <<= 1) s += __shfl_xor(s, mk, 64);
    if ((threadIdx.x & 63) == 0) red[threadIdx.x >> 6] = s;
    __syncthreads();
    if (threadIdx.x == 0)
        out[0] = red[0] + red[1] + red[2] + red[3];
}

extern "C" void kernel_launch(void* const* d_in, const int* in_sizes, int n_in,
                              void* d_out, int out_size, void* d_ws, size_t ws_size,
                              hipStream_t stream) {
    const int*   events = (const int*)  d_in[0];   // event_seqs  [B,L] int32
    const int*   lens   = (const int*)  d_in[1];   // seqs_length [B]   int32
    const float* ttime  = (const float*)d_in[2];   // total_time  [B]
    const float* hidden = (const float*)d_in[3];   // [L,B,H]
    const float* cell   = (const float*)d_in[4];   // [L,B,H]
    const float* ctarg  = (const float*)d_in[5];   // [L,B,H]
    const float* outp   = (const float*)d_in[6];   // [L,B,H]
    const float* decay  = (const float*)d_in[7];   // [L,B,H]
    const float* simt   = (const float*)d_in[8];   // [L,B]
    const float* W      = (const float*)d_in[9];   // [H,K]
    const float* bias   = (const float*)d_in[10];  // [K]

    float* part = (float*)d_ws;                    // NBLK floats
    float* out  = (float*)d_out;

    nhll_main<<<NBLK, 256, 0, stream>>>(events, lens, ttime, hidden, cell, ctarg,
                                        outp, decay, simt, W, bias, part);
    nhll_finalize<<<1, 256, 0, stream>>>(part, out);
}